// Round 22
// baseline (124.964 us; speedup 1.0000x reference)
//
#include <hip/hip_runtime.h>

// ImageLRU as one GEMM: y[r,:] = W @ x[r,:], W (1024x1024, block-lower-tri)
// built on device. R22: split pipeline, every stage isolated + minimal.
//   Diagnosis R18-R21: fused gemm is L3-BW-bound staging fp32 A (536 MB at
//   ~5-6 B/cy/CU = the 2.2us/tile-step); bf16-A split gemms measured 40-45us.
//   Pipeline: (1) build_w alone; (2) PURE contiguous cast X->row-major Xh
//   (float4->ushort4, both sides coalesced, first clean measurement);
//   (3) R17 gemm verbatim (tri-buffer, counted vmcnt(6), BN=256, per-lane
//   row-major A sources) + 2-bit XOR source swizzle (A-frag conflict 8->4 way).
//   1-term precision: y = bf16(X)*bf16(W)  (absmax 8192, thr 32768).

namespace {

typedef __attribute__((ext_vector_type(8))) short short8v;
typedef __attribute__((ext_vector_type(4))) float f32x4;

__device__ inline unsigned short f2bf_rne(float f) {
    unsigned u = __builtin_bit_cast(unsigned, f);
    u += 0x7fffu + ((u >> 16) & 1u);
    return (unsigned short)(u >> 16);
}

__device__ inline void gld_lds16(const unsigned short* g, unsigned short* l) {
    __builtin_amdgcn_global_load_lds(
        (const __attribute__((address_space(1))) unsigned int*)g,
        (__attribute__((address_space(3))) unsigned int*)l, 16, 0, 0);
}

// W tile ([256 n][32 k], 8192 ushorts, kg-major): (n,k) at
//   base + ((k>>3)<<11) + (n<<3) + (k&7)
// Xh: plain row-major [32768][1024] bf16.
// A LDS image per tile: [128 rows][4 kq-slots of 8 ushorts], slot kq holds
//   global k-group kq^(row&3)  -> frag reads 4-way-spread banks.

// ---------------- prep 1: build Wh (bf16) in [256n][32k] tiles --------------
__global__ __launch_bounds__(256) void build_w_kernel(
    const float* __restrict__ Lre, const float* __restrict__ Lim,
    const float* __restrict__ Bre, const float* __restrict__ Bim,
    const float* __restrict__ Cre, const float* __restrict__ Cim,
    const float* __restrict__ Dm,
    unsigned short* __restrict__ Wh)
{
    const int i = blockIdx.x >> 6, j = blockIdx.x & 63;
    const int t = threadIdx.x, k = t >> 4, l = t & 15;

    const int n_g = i * 16 + k;        // W row (n dim)
    const int k_g = j * 16 + l;        // W col (k dim)
    const size_t widx = (((size_t)((n_g >> 8) * 32 + (k_g >> 5))) << 13)
                      + (((k_g >> 3) & 3) << 11) + ((n_g & 255) << 3) + (k_g & 7);

    if (j > i) { Wh[widx] = 0; return; }

    __shared__ float2 Bs[16][16];
    __shared__ float2 M[16][16];
    Bs[k][l] = make_float2(Bre[t], Bim[t]);
    M[k][l]  = make_float2(k == l ? 1.f : 0.f, 0.f);
    const int delta = i - j;
    __syncthreads();

    #pragma unroll
    for (int d = 0; d < 6; ++d) {
        const int s = 1 << d;
        if (delta & s) {
            const float lr = Lre[k], li = Lim[k];
            const float2 m0 = M[k][l];
            M[k][l] = make_float2(lr * m0.x - li * m0.y, lr * m0.y + li * m0.x);
            __syncthreads();
        } else if (j + (delta & (s - 1)) >= s) {
            float2 acc = make_float2(0.f, 0.f);
            #pragma unroll
            for (int m = 0; m < 16; ++m) {
                const float2 b = Bs[k][m], v = M[m][l];
                acc.x += b.x * v.x - b.y * v.y;
                acc.y += b.x * v.y + b.y * v.x;
            }
            __syncthreads();
            M[k][l] = acc;
            __syncthreads();
        }
    }

    float w = 0.f;
    #pragma unroll
    for (int m = 0; m < 16; ++m) {
        const float2 v = M[m][l];
        w += Cre[k * 16 + m] * v.x - Cim[k * 16 + m] * v.y;
    }
    if (i == j) w += Dm[t];
    Wh[widx] = f2bf_rne(w);
}

// ---------------- prep 2: pure contiguous cast X -> Xh (row-major) ----------
__global__ __launch_bounds__(256) void cast_x_kernel(
    const float* __restrict__ X, unsigned short* __restrict__ Xh, int n4)
{
    // one float4 (16B, wave-contiguous 1KB) -> one ushort4 (8B, 512B/wave)
    const int stride = gridDim.x * 256;
    for (int i = blockIdx.x * 256 + threadIdx.x; i < n4; i += stride) {
        const float4 v = *reinterpret_cast<const float4*>(X + (size_t)i * 4);
        ushort4 h;
        h.x = f2bf_rne(v.x);
        h.y = f2bf_rne(v.y);
        h.z = f2bf_rne(v.z);
        h.w = f2bf_rne(v.w);
        *reinterpret_cast<ushort4*>(Xh + (size_t)i * 4) = h;
    }
}

// ---- main GEMM (R17 + src swizzle): 128x256, tri-buffer, counted vmcnt -----
__global__ __launch_bounds__(256, 2) void gemm_cnt_kernel(
    const unsigned short* __restrict__ Xh,
    const unsigned short* __restrict__ Wh,
    float* __restrict__ Y, int mtiles)
{
    __shared__ alignas(16) unsigned short sA[3][4096];   // 24 KB
    __shared__ alignas(16) unsigned short sB[3][8192];   // 48 KB

    const int bid = blockIdx.x;
    const int sb = 3 - bid / mtiles;   // 256-col supertile, heavy first (LPT)
    const int mt = bid % mtiles;
    const int t = threadIdx.x;
    const int wid = t >> 6, lane = t & 63;
    const int wr = wid >> 1, wc = wid & 1;     // 2Mx2N wave grid
    const int l15 = lane & 15, lg = lane >> 4;
    const int nt = (sb + 1) * 8;       // K-tiles of 32 (8,16,24,32)

    f32x4 acc[4][8] = {};

    // A-frag offsets in swizzled LDS image: row*32 + (lg^(row&3))*8 ushorts
    int afo[4], bfo[8];
    #pragma unroll
    for (int mm = 0; mm < 4; ++mm) {
        const int row = wr * 64 + mm * 16 + l15;
        afo[mm] = (row << 5) + ((lg ^ (row & 3)) << 3);
    }
    #pragma unroll
    for (int nn = 0; nn < 8; ++nn)
        bfo[nn] = (lg << 11) + ((wc * 128 + nn * 16 + l15) << 3);

    // per-lane A source offsets (ushorts): slot s: row=s>>2, kq=s&3;
    // fetch global k-group kq^(row&3)   (source-side of the swizzle)
    const int arow0 = t >> 2, akq = t & 3;
    const size_t asrc0 = (size_t)arow0 * 1024 + ((akq ^ (arow0 & 3)) * 8);
    const size_t asrc1 = (size_t)(64 + arow0) * 1024 + ((akq ^ (arow0 & 3)) * 8);

    auto stageT = [&](int b3, int tk) {        // 6 gld_lds16 per thread
        unsigned short* bA = sA[b3];
        unsigned short* bB = sB[b3];
        const unsigned short* xa = Xh + ((size_t)mt << 17) + tk * 32;  // mt*128*1024
        const unsigned short* wb = Wh + (((size_t)(sb * 32 + tk)) << 13);
        gld_lds16(xa + asrc0, bA + t * 8);
        gld_lds16(xa + asrc1, bA + 2048 + t * 8);
        gld_lds16(wb + t * 8,        bB + t * 8);
        gld_lds16(wb + 2048 + t * 8, bB + 2048 + t * 8);
        gld_lds16(wb + 4096 + t * 8, bB + 4096 + t * 8);
        gld_lds16(wb + 6144 + t * 8, bB + 6144 + t * 8);
    };

    stageT(0, 0);
    stageT(1, 1);
    asm volatile("s_waitcnt vmcnt(6)" ::: "memory");
    __builtin_amdgcn_sched_barrier(0);
    __builtin_amdgcn_s_barrier();
    __builtin_amdgcn_sched_barrier(0);

    int c = 0, c2 = 2;                 // tk%3, (tk+2)%3
    for (int tk = 0; tk < nt; ++tk) {
        if (tk + 2 < nt) stageT(c2, tk + 2);

        short8v ah[4], bh[8];
        #pragma unroll
        for (int mm = 0; mm < 4; ++mm)
            ah[mm] = *reinterpret_cast<const short8v*>(sA[c] + afo[mm]);
        #pragma unroll
        for (int nn = 0; nn < 8; ++nn)
            bh[nn] = *reinterpret_cast<const short8v*>(sB[c] + bfo[nn]);

        __builtin_amdgcn_s_setprio(1);
        #pragma unroll
        for (int mm = 0; mm < 4; ++mm)
            #pragma unroll
            for (int nn = 0; nn < 8; ++nn)
                acc[mm][nn] = __builtin_amdgcn_mfma_f32_16x16x32_bf16(
                    ah[mm], bh[nn], acc[mm][nn], 0, 0, 0);
        __builtin_amdgcn_s_setprio(0);

        if (tk + 1 < nt) {             // tile boundary
            if (tk + 2 < nt) {
                asm volatile("s_waitcnt vmcnt(6)" ::: "memory");
            } else {
                asm volatile("s_waitcnt vmcnt(0)" ::: "memory");
            }
            __builtin_amdgcn_sched_barrier(0);
            __builtin_amdgcn_s_barrier();
            __builtin_amdgcn_sched_barrier(0);
        }
        c = (c == 2) ? 0 : c + 1;
        c2 = (c2 == 2) ? 0 : c2 + 1;
    }

    // ---- epilogue: C/D layout col=lane&15, row=(lane>>4)*4+q ----
    #pragma unroll
    for (int mm = 0; mm < 4; ++mm) {
        const int grow = mt * 128 + wr * 64 + mm * 16 + lg * 4;
        #pragma unroll
        for (int nn = 0; nn < 8; ++nn) {
            const int gcol = sb * 256 + wc * 128 + nn * 16 + l15;
            #pragma unroll
            for (int q = 0; q < 4; ++q)
                Y[(size_t)(grow + q) * 1024 + gcol] = acc[mm][nn][q];
        }
    }
}

} // namespace

extern "C" void kernel_launch(void* const* d_in, const int* in_sizes, int n_in,
                              void* d_out, int out_size, void* d_ws, size_t ws_size,
                              hipStream_t stream) {
    const float* x   = (const float*)d_in[0];
    const float* Lre = (const float*)d_in[1];
    const float* Lim = (const float*)d_in[2];
    const float* Bre = (const float*)d_in[3];
    const float* Bim = (const float*)d_in[4];
    const float* Cre = (const float*)d_in[5];
    const float* Cim = (const float*)d_in[6];
    const float* Dm  = (const float*)d_in[7];
    float* y = (float*)d_out;

    const int positions = in_sizes[0] / 1024;          // 32768
    const int mtiles = positions / 128;                // 256
    const int n4 = in_sizes[0] / 4;                    // float4 count

    unsigned short* Wh = (unsigned short*)d_ws;        // 2 MB
    unsigned short* Xh = Wh + 1024 * 1024;             // 64 MB

    build_w_kernel<<<4096, 256, 0, stream>>>(Lre, Lim, Bre, Bim, Cre, Cim, Dm, Wh);
    cast_x_kernel<<<2048, 256, 0, stream>>>(x, Xh, n4);
    gemm_cnt_kernel<<<mtiles * 4, 256, 0, stream>>>(Xh, Wh, y, mtiles);
}

// Round 23
// 96.675 us; speedup vs baseline: 1.2926x; 1.2926x over previous
//
#include <hip/hip_runtime.h>
#include <hip/hip_bf16.h>

// ImageLRU as one GEMM: y[r,:] = W @ x[r,:], W (1024x1024, block-lower-tri)
// built on device. R23 = R18 fused-cast GEMM + split-depth counted vmcnt:
//  - A (fp32, slow L3/HBM path): 3 LDS buffers, staged 2 steps ahead.
//  - W (bf16, L2-resident):      2 LDS buffers, staged 1 step ahead.
//  - Per step: issue W(t+1) then A(t+2); barrier waits vmcnt(4) -> A(t+1)
//    and W(t+1) landed, A(t+2)'s 4 loads FLY ACROSS the barrier. Never
//    drain to 0 mid-loop (m218 lever). All loop VMEM ops are gld_lds
//    builtins in program order -> exact FIFO ledger (m135).
//  - LDS 3x16(A) + 2x16(W) = 80 KB -> 2 blocks/CU (R18 occupancy kept).
//  - Rest R18-verbatim: BM=128xBN=256, 4 waves 2Mx2N, acc[4][8], per-lane
//    XOR-swizzled A sources (chunk kq^(row&7)), cvt_pk at frag read,
//    kg-major [256n][32k] W tiles, sb-major LPT, setprio on MFMA cluster.
//  1-term precision: y = bf16(X)*bf16(W)  (absmax 8192, thr 32768).

namespace {

typedef __attribute__((ext_vector_type(8))) short short8v;
typedef __attribute__((ext_vector_type(4))) float f32x4;
typedef __attribute__((ext_vector_type(4))) unsigned uint4v;

__device__ inline unsigned short f2bf_rne(float f) {
    unsigned u = __builtin_bit_cast(unsigned, f);
    u += 0x7fffu + ((u >> 16) & 1u);
    return (unsigned short)(u >> 16);
}

__device__ inline void gld_lds16(const unsigned short* g, unsigned short* l) {
    __builtin_amdgcn_global_load_lds(
        (const __attribute__((address_space(1))) unsigned int*)g,
        (__attribute__((address_space(3))) unsigned int*)l, 16, 0, 0);
}

__device__ inline unsigned pk2(float a, float b) {
    __hip_bfloat162 h = __float22bfloat162_rn(make_float2(a, b));
    unsigned r;
    __builtin_memcpy(&r, &h, 4);
    return r;
}

// W tile ([256 n][32 k], 8192 ushorts, kg-major): (n,k) at
//   base + ((k>>3)<<11) + (n<<3) + (k&7)
// A LDS tile: fp32 [128 rows][32 k] row-major; 16B chunk kq stored at
//   slot (row, kq^(row&7)) -> frag reads bank-uniform.

// ---------------- prep: build Wh (bf16) in [256n][32k] tiles ----------------
__global__ __launch_bounds__(256) void build_w_kernel(
    const float* __restrict__ Lre, const float* __restrict__ Lim,
    const float* __restrict__ Bre, const float* __restrict__ Bim,
    const float* __restrict__ Cre, const float* __restrict__ Cim,
    const float* __restrict__ Dm,
    unsigned short* __restrict__ Wh)
{
    const int i = blockIdx.x >> 6, j = blockIdx.x & 63;
    const int t = threadIdx.x, k = t >> 4, l = t & 15;

    const int n_g = i * 16 + k;        // W row (n dim)
    const int k_g = j * 16 + l;        // W col (k dim)
    const size_t widx = (((size_t)((n_g >> 8) * 32 + (k_g >> 5))) << 13)
                      + (((k_g >> 3) & 3) << 11) + ((n_g & 255) << 3) + (k_g & 7);

    if (j > i) { Wh[widx] = 0; return; }

    __shared__ float2 Bs[16][16];
    __shared__ float2 M[16][16];
    Bs[k][l] = make_float2(Bre[t], Bim[t]);
    M[k][l]  = make_float2(k == l ? 1.f : 0.f, 0.f);
    const int delta = i - j;
    __syncthreads();

    #pragma unroll
    for (int d = 0; d < 6; ++d) {
        const int s = 1 << d;
        if (delta & s) {
            const float lr = Lre[k], li = Lim[k];
            const float2 m0 = M[k][l];
            M[k][l] = make_float2(lr * m0.x - li * m0.y, lr * m0.y + li * m0.x);
            __syncthreads();
        } else if (j + (delta & (s - 1)) >= s) {
            float2 acc = make_float2(0.f, 0.f);
            #pragma unroll
            for (int m = 0; m < 16; ++m) {
                const float2 b = Bs[k][m], v = M[m][l];
                acc.x += b.x * v.x - b.y * v.y;
                acc.y += b.x * v.y + b.y * v.x;
            }
            __syncthreads();
            M[k][l] = acc;
            __syncthreads();
        }
    }

    float w = 0.f;
    #pragma unroll
    for (int m = 0; m < 16; ++m) {
        const float2 v = M[m][l];
        w += Cre[k * 16 + m] * v.x - Cim[k * 16 + m] * v.y;
    }
    if (i == j) w += Dm[t];
    Wh[widx] = f2bf_rne(w);
}

// --- main GEMM: fused cvt, A tri-buf (2-step) + W dbuf (1-step), vmcnt(4) ---
__global__ __launch_bounds__(256, 2) void gemm_fused_kernel(
    const float* __restrict__ X,
    const unsigned short* __restrict__ Wh,
    float* __restrict__ Y, int mtiles)
{
    __shared__ alignas(16) float sA[3][4096];            // 48 KB fp32 A
    __shared__ alignas(16) unsigned short sB[2][8192];   // 32 KB bf16 W

    const int bid = blockIdx.x;
    const int sb = 3 - bid / mtiles;   // 256-col supertile, heavy first (LPT)
    const int mt = bid % mtiles;
    const int t = threadIdx.x;
    const int wid = t >> 6, lane = t & 63;
    const int wr = wid >> 1, wc = wid & 1;     // 2Mx2N wave grid
    const int l15 = lane & 15, lg = lane >> 4;
    const int nt = (sb + 1) * 8;       // K-tiles of 32 (8,16,24,32)

    f32x4 acc[4][8] = {};

    // A frag read offsets (floats): row*32 + ((2lg+e)^(row&7))*4
    int arow[4], as0[4], as1[4];
    #pragma unroll
    for (int mm = 0; mm < 4; ++mm) {
        const int row = wr * 64 + mm * 16 + l15;
        arow[mm] = row << 5;
        as0[mm] = (((2 * lg)     ^ (row & 7)) << 2);
        as1[mm] = (((2 * lg + 1) ^ (row & 7)) << 2);
    }
    // B frag offsets (ushorts) within a [256n][32k] W tile
    int bfo[8];
    #pragma unroll
    for (int nn = 0; nn < 8; ++nn)
        bfo[nn] = (lg << 11) + ((wc * 128 + nn * 16 + l15) << 3);

    auto stageA = [&](int b, int tk) {         // 4 gld_lds16 per thread
        float* bA = sA[b];
        const float* xbase = X + (size_t)mt * 131072 + tk * 32;  // mt*128*1024
        #pragma unroll
        for (int p = 0; p < 4; ++p) {
            const int s = p * 256 + t;
            const int row = s >> 3, kq = s & 7;
            const float* src = xbase + (size_t)row * 1024 + ((kq ^ (row & 7)) << 2);
            gld_lds16((const unsigned short*)src, (unsigned short*)(bA + s * 4));
        }
    };
    auto stageW = [&](int b, int tk) {         // 4 gld_lds16 per thread
        unsigned short* bB = sB[b];
        const unsigned short* wb = Wh + (((size_t)(sb * 32 + tk)) << 13);
        #pragma unroll
        for (int p = 0; p < 4; ++p) {
            const int e8 = (p * 256 + t) * 8;
            gld_lds16(wb + e8, bB + e8);
        }
    };

    // prologue: A0, W0 (must land), A1 (may fly) -- issue order matters (FIFO)
    stageA(0, 0);
    stageW(0, 0);
    stageA(1, 1);
    asm volatile("s_waitcnt vmcnt(4)" ::: "memory");   // A0,W0 landed; A1 flies
    __builtin_amdgcn_sched_barrier(0);
    __builtin_amdgcn_s_barrier();
    __builtin_amdgcn_sched_barrier(0);

    int cA = 0, cA2 = 2;               // tk%3, (tk+2)%3
    for (int tk = 0; tk < nt; ++tk) {
        const int cW = tk & 1;
        if (tk + 2 < nt) {
            stageW(cW ^ 1, tk + 1);    // older: must land this step (L2, fast)
            stageA(cA2, tk + 2);       // newer: flies across next barrier
        } else if (tk + 1 < nt) {
            stageW(cW ^ 1, tk + 1);
        }

        // A fragments: fp32 LDS reads (swizzled, bank-uniform) + cvt_pk
        short8v ah[4];
        #pragma unroll
        for (int mm = 0; mm < 4; ++mm) {
            const f32x4 q0 = *reinterpret_cast<const f32x4*>(sA[cA] + arow[mm] + as0[mm]);
            const f32x4 q1 = *reinterpret_cast<const f32x4*>(sA[cA] + arow[mm] + as1[mm]);
            uint4v uv;
            uv[0] = pk2(q0[0], q0[1]);
            uv[1] = pk2(q0[2], q0[3]);
            uv[2] = pk2(q1[0], q1[1]);
            uv[3] = pk2(q1[2], q1[3]);
            short8v r;
            __builtin_memcpy(&r, &uv, 16);
            ah[mm] = r;
        }
        short8v bh[8];
        #pragma unroll
        for (int nn = 0; nn < 8; ++nn)
            bh[nn] = *reinterpret_cast<const short8v*>(sB[cW] + bfo[nn]);

        __builtin_amdgcn_s_setprio(1);
        #pragma unroll
        for (int mm = 0; mm < 4; ++mm)
            #pragma unroll
            for (int nn = 0; nn < 8; ++nn)
                acc[mm][nn] = __builtin_amdgcn_mfma_f32_16x16x32_bf16(
                    ah[mm], bh[nn], acc[mm][nn], 0, 0, 0);
        __builtin_amdgcn_s_setprio(0);

        if (tk + 1 < nt) {             // tile boundary
            if (tk + 2 < nt) {
                asm volatile("s_waitcnt vmcnt(4)" ::: "memory");  // A(t+2) flies
            } else {
                asm volatile("s_waitcnt vmcnt(0)" ::: "memory");  // tail drain
            }
            __builtin_amdgcn_sched_barrier(0);
            __builtin_amdgcn_s_barrier();
            __builtin_amdgcn_sched_barrier(0);
        }
        cA = (cA == 2) ? 0 : cA + 1;
        cA2 = (cA2 == 2) ? 0 : cA2 + 1;
    }

    // ---- epilogue: C/D layout col=lane&15, row=(lane>>4)*4+q ----
    #pragma unroll
    for (int mm = 0; mm < 4; ++mm) {
        const int grow = mt * 128 + wr * 64 + mm * 16 + lg * 4;
        #pragma unroll
        for (int nn = 0; nn < 8; ++nn) {
            const int gcol = sb * 256 + wc * 128 + nn * 16 + l15;
            #pragma unroll
            for (int q = 0; q < 4; ++q)
                Y[(size_t)(grow + q) * 1024 + gcol] = acc[mm][nn][q];
        }
    }
}

} // namespace

extern "C" void kernel_launch(void* const* d_in, const int* in_sizes, int n_in,
                              void* d_out, int out_size, void* d_ws, size_t ws_size,
                              hipStream_t stream) {
    const float* x   = (const float*)d_in[0];
    const float* Lre = (const float*)d_in[1];
    const float* Lim = (const float*)d_in[2];
    const float* Bre = (const float*)d_in[3];
    const float* Bim = (const float*)d_in[4];
    const float* Cre = (const float*)d_in[5];
    const float* Cim = (const float*)d_in[6];
    const float* Dm  = (const float*)d_in[7];
    float* y = (float*)d_out;

    const int positions = in_sizes[0] / 1024;          // 32768
    const int mtiles = positions / 128;                // 256

    unsigned short* Wh = (unsigned short*)d_ws;        // 2 MB

    build_w_kernel<<<4096, 256, 0, stream>>>(Lre, Lim, Bre, Bim, Cre, Cim, Dm, Wh);
    gemm_fused_kernel<<<mtiles * 4, 256, 0, stream>>>(x, Wh, y, mtiles);
}